// Round 1
// baseline (699.117 us; speedup 1.0000x reference)
//
#include <hip/hip_runtime.h>

#define N_NODES 100000
#define N_EDGES 2500000

// ---------------------------------------------------------------------------
// Edge pass 1: deg[dst] += 1; s1[dst] += x[src]  (2 features)
// ---------------------------------------------------------------------------
__global__ void edge_agg1(const int* __restrict__ ei, const float* __restrict__ x,
                          float* __restrict__ deg, float* __restrict__ s1) {
    int e = blockIdx.x * blockDim.x + threadIdx.x;
    if (e >= N_EDGES) return;
    int src = ei[e];
    int dst = ei[N_EDGES + e];
    float2 v = *reinterpret_cast<const float2*>(x + 2 * src);
    atomicAdd(&deg[dst], 1.0f);
    atomicAdd(&s1[2 * dst], v.x);
    atomicAdd(&s1[2 * dst + 1], v.y);
}

// ---------------------------------------------------------------------------
// Node pass 1: deg_inv, hidden h (32, in registers only), h2 = h@W_l2, hr = h@W_r2
// ---------------------------------------------------------------------------
__global__ void node1(const float* __restrict__ x, float* __restrict__ deg_io,
                      const float* __restrict__ s1,
                      const float* __restrict__ Wl1, const float* __restrict__ Wr1,
                      const float* __restrict__ b1,
                      const float* __restrict__ Wl2, const float* __restrict__ Wr2,
                      float* __restrict__ h2, float* __restrict__ hr) {
    __shared__ float sWl1[64], sWr1[64], sb1[32], sWl2[64], sWr2[64];
    int t = threadIdx.x;
    if (t < 64) {
        sWl1[t] = Wl1[t];
        sWr1[t] = Wr1[t];
        sWl2[t] = Wl2[t];
        sWr2[t] = Wr2[t];
    }
    if (t < 32) sb1[t] = b1[t];
    __syncthreads();

    int i = blockIdx.x * blockDim.x + t;
    if (i >= N_NODES) return;

    float d = deg_io[i];
    float dinv = 1.0f / fmaxf(d, 1.0f);
    deg_io[i] = dinv;  // reuse buffer: deg -> deg_inv

    float ax = s1[2 * i] * dinv;
    float ay = s1[2 * i + 1] * dinv;
    float xx = x[2 * i];
    float xy = x[2 * i + 1];

    float h2a = 0.f, h2b = 0.f, hra = 0.f, hrb = 0.f;
#pragma unroll
    for (int f = 0; f < 32; ++f) {
        // W_l1 is [2,32] row-major; W_l2/W_r2 are [32,2] row-major
        float h = ax * sWl1[f] + ay * sWl1[32 + f] + xx * sWr1[f] + xy * sWr1[32 + f] + sb1[f];
        h = fmaxf(h, 0.0f);
        h2a += h * sWl2[2 * f];
        h2b += h * sWl2[2 * f + 1];
        hra += h * sWr2[2 * f];
        hrb += h * sWr2[2 * f + 1];
    }
    h2[2 * i] = h2a;
    h2[2 * i + 1] = h2b;
    hr[2 * i] = hra;
    hr[2 * i + 1] = hrb;
}

// ---------------------------------------------------------------------------
// Edge pass 2: s2[dst] += h2[src]  (2 features; W_l2 pre-applied)
// ---------------------------------------------------------------------------
__global__ void edge_agg2(const int* __restrict__ ei, const float* __restrict__ h2,
                          float* __restrict__ s2) {
    int e = blockIdx.x * blockDim.x + threadIdx.x;
    if (e >= N_EDGES) return;
    int src = ei[e];
    int dst = ei[N_EDGES + e];
    float2 v = *reinterpret_cast<const float2*>(h2 + 2 * src);
    atomicAdd(&s2[2 * dst], v.x);
    atomicAdd(&s2[2 * dst + 1], v.y);
}

// ---------------------------------------------------------------------------
// Node pass 2: out = log_softmax(s2*deg_inv + hr + b2)
// ---------------------------------------------------------------------------
__global__ void node2(const float* __restrict__ deg_inv, const float* __restrict__ s2,
                      const float* __restrict__ hr, const float* __restrict__ b2,
                      float* __restrict__ out) {
    int i = blockIdx.x * blockDim.x + threadIdx.x;
    if (i >= N_NODES) return;
    float dinv = deg_inv[i];
    float o0 = s2[2 * i] * dinv + hr[2 * i] + b2[0];
    float o1 = s2[2 * i + 1] * dinv + hr[2 * i + 1] + b2[1];
    float m = fmaxf(o0, o1);
    float e0 = expf(o0 - m);
    float e1 = expf(o1 - m);
    float lse = logf(e0 + e1);
    out[2 * i] = o0 - m - lse;
    out[2 * i + 1] = o1 - m - lse;
}

extern "C" void kernel_launch(void* const* d_in, const int* in_sizes, int n_in,
                              void* d_out, int out_size, void* d_ws, size_t ws_size,
                              hipStream_t stream) {
    const float* x   = (const float*)d_in[0];
    const int*   ei  = (const int*)d_in[1];
    const float* Wl1 = (const float*)d_in[2];
    const float* Wr1 = (const float*)d_in[3];
    const float* b1  = (const float*)d_in[4];
    const float* Wl2 = (const float*)d_in[5];
    const float* Wr2 = (const float*)d_in[6];
    const float* b2  = (const float*)d_in[7];
    float* out = (float*)d_out;

    float* ws  = (float*)d_ws;
    float* deg = ws;                  // [N]      -> becomes deg_inv after node1
    float* s1  = ws + 1 * N_NODES;    // [N,2]
    float* s2  = ws + 3 * N_NODES;    // [N,2]
    float* h2  = ws + 5 * N_NODES;    // [N,2]
    float* hr  = ws + 7 * N_NODES;    // [N,2]

    // zero the atomic accumulators (deg, s1, s2 are contiguous: 5N floats)
    hipMemsetAsync(deg, 0, (size_t)5 * N_NODES * sizeof(float), stream);

    const int EB = 256;
    const int EG = (N_EDGES + EB - 1) / EB;
    const int NB = 256;
    const int NG = (N_NODES + NB - 1) / NB;

    edge_agg1<<<EG, EB, 0, stream>>>(ei, x, deg, s1);
    node1<<<NG, NB, 0, stream>>>(x, deg, s1, Wl1, Wr1, b1, Wl2, Wr2, h2, hr);
    edge_agg2<<<EG, EB, 0, stream>>>(ei, h2, s2);
    node2<<<NG, NB, 0, stream>>>(deg, s2, hr, b2, out);
}

// Round 2
// 311.096 us; speedup vs baseline: 2.2473x; 2.2473x over previous
//
#include <hip/hip_runtime.h>

#define N_NODES 100000
#define N_EDGES 2500000

// pass-1 fixed point: fields [fy:28 | fx:28 | cnt:8], bias 16, scale 2^16
// per-edge biased value < (16+16)*2^16 = 2^21; deg <= 128 -> field sum < 2^28 (no carry)
#define B1 16.0f
#define S1 65536.0f
// pass-2 fixed point: fields [fy:32 | fx:32], bias 2048, scale 2^12
// per-edge biased value < (600+2048)*2^12 < 2^24; deg <= 128 -> sum < 2^31 (no carry)
#define B2 2048.0f
#define S2 4096.0f

typedef unsigned long long u64;
typedef unsigned int u32;

// ---------------------------------------------------------------------------
// Encode x per node: one u64 per node = [ (y+B1)*S1 : 28 | (x+B1)*S1 : 28 | 1 : 8 ]
// ---------------------------------------------------------------------------
__global__ void encode_x(const float* __restrict__ x, u64* __restrict__ encx) {
    int i = blockIdx.x * blockDim.x + threadIdx.x;
    if (i >= N_NODES) return;
    float2 v = reinterpret_cast<const float2*>(x)[i];
    u64 fx = (u64)(u32)((v.x + B1) * S1 + 0.5f);
    u64 fy = (u64)(u32)((v.y + B1) * S1 + 0.5f);
    encx[i] = (fy << 36) | (fx << 8) | 1ull;
}

// ---------------------------------------------------------------------------
// Generic edge pass: acc[dst] += table[src]  (ONE u64 atomic per edge)
// ---------------------------------------------------------------------------
__global__ void edge_pass(const int* __restrict__ ei, const u64* __restrict__ table,
                          u64* __restrict__ acc) {
    int e = blockIdx.x * blockDim.x + threadIdx.x;
    if (e >= N_EDGES) return;
    int src = ei[e];
    int dst = ei[N_EDGES + e];
    atomicAdd(&acc[dst], table[src]);
}

// ---------------------------------------------------------------------------
// Node pass 1: decode s1 -> mean agg; hidden h in registers; emit encoded h2,
// hr = h@W_r2, degf
// ---------------------------------------------------------------------------
__global__ void node1(const float* __restrict__ x, const u64* __restrict__ s1,
                      const float* __restrict__ Wl1, const float* __restrict__ Wr1,
                      const float* __restrict__ b1,
                      const float* __restrict__ Wl2, const float* __restrict__ Wr2,
                      u64* __restrict__ ench2, float2* __restrict__ hr,
                      float* __restrict__ degf) {
    __shared__ float sWl1[64], sWr1[64], sb1[32], sWl2[64], sWr2[64];
    int t = threadIdx.x;
    if (t < 64) {
        sWl1[t] = Wl1[t];
        sWr1[t] = Wr1[t];
        sWl2[t] = Wl2[t];
        sWr2[t] = Wr2[t];
    }
    if (t < 32) sb1[t] = b1[t];
    __syncthreads();

    int i = blockIdx.x * blockDim.x + t;
    if (i >= N_NODES) return;

    u64 v = s1[i];
    float cnt = (float)(u32)(v & 0xFFull);
    double fx = (double)(u32)((v >> 8) & 0xFFFFFFFull);
    double fy = (double)(v >> 36);
    float dinv = 1.0f / fmaxf(cnt, 1.0f);
    float ax = (float)(fx * (1.0 / 65536.0) - (double)cnt * 16.0) * dinv;
    float ay = (float)(fy * (1.0 / 65536.0) - (double)cnt * 16.0) * dinv;

    float2 xv = reinterpret_cast<const float2*>(x)[i];

    float h2a = 0.f, h2b = 0.f, hra = 0.f, hrb = 0.f;
#pragma unroll
    for (int f = 0; f < 32; ++f) {
        float h = ax * sWl1[f] + ay * sWl1[32 + f] + xv.x * sWr1[f] + xv.y * sWr1[32 + f] + sb1[f];
        h = fmaxf(h, 0.0f);
        h2a += h * sWl2[2 * f];
        h2b += h * sWl2[2 * f + 1];
        hra += h * sWr2[2 * f];
        hrb += h * sWr2[2 * f + 1];
    }
    u32 ex = (u32)((h2a + B2) * S2 + 0.5f);
    u32 ey = (u32)((h2b + B2) * S2 + 0.5f);
    ench2[i] = ((u64)ey << 32) | (u64)ex;
    hr[i] = make_float2(hra, hrb);
    degf[i] = cnt;
}

// ---------------------------------------------------------------------------
// Node pass 2: decode s2, combine, log_softmax
// ---------------------------------------------------------------------------
__global__ void node2(const float* __restrict__ degf, const u64* __restrict__ s2,
                      const float2* __restrict__ hr, const float* __restrict__ b2,
                      float* __restrict__ out) {
    int i = blockIdx.x * blockDim.x + threadIdx.x;
    if (i >= N_NODES) return;
    float deg = degf[i];
    float dinv = 1.0f / fmaxf(deg, 1.0f);
    u64 v = s2[i];
    double fx = (double)(u32)(v & 0xFFFFFFFFull);
    double fy = (double)(v >> 32);
    float sx = (float)(fx * (1.0 / 4096.0) - (double)deg * 2048.0);
    float sy = (float)(fy * (1.0 / 4096.0) - (double)deg * 2048.0);
    float2 hv = hr[i];
    float o0 = sx * dinv + hv.x + b2[0];
    float o1 = sy * dinv + hv.y + b2[1];
    float m = fmaxf(o0, o1);
    float e0 = expf(o0 - m);
    float e1 = expf(o1 - m);
    float lse = logf(e0 + e1);
    float2 o = make_float2(o0 - m - lse, o1 - m - lse);
    reinterpret_cast<float2*>(out)[i] = o;
}

extern "C" void kernel_launch(void* const* d_in, const int* in_sizes, int n_in,
                              void* d_out, int out_size, void* d_ws, size_t ws_size,
                              hipStream_t stream) {
    const float* x   = (const float*)d_in[0];
    const int*   ei  = (const int*)d_in[1];
    const float* Wl1 = (const float*)d_in[2];
    const float* Wr1 = (const float*)d_in[3];
    const float* b1  = (const float*)d_in[4];
    const float* Wl2 = (const float*)d_in[5];
    const float* Wr2 = (const float*)d_in[6];
    const float* b2  = (const float*)d_in[7];
    float* out = (float*)d_out;

    u64* w64 = (u64*)d_ws;
    u64* s1    = w64;                 // [N] packed accumulators (layer 1)
    u64* s2    = w64 + N_NODES;       // [N] packed accumulators (layer 2)
    u64* encx  = w64 + 2 * N_NODES;   // [N] encoded x table
    u64* ench2 = w64 + 3 * N_NODES;   // [N] encoded h2 table
    float* fws  = (float*)(w64 + 4 * N_NODES);
    float2* hr  = (float2*)fws;       // [N] float2
    float* degf = fws + 2 * N_NODES;  // [N]

    // zero the two packed accumulator arrays (contiguous)
    hipMemsetAsync(s1, 0, (size_t)2 * N_NODES * sizeof(u64), stream);

    const int EB = 256;
    const int EG = (N_EDGES + EB - 1) / EB;
    const int NB = 256;
    const int NG = (N_NODES + NB - 1) / NB;

    encode_x<<<NG, NB, 0, stream>>>(x, encx);
    edge_pass<<<EG, EB, 0, stream>>>(ei, encx, s1);
    node1<<<NG, NB, 0, stream>>>(x, s1, Wl1, Wr1, b1, Wl2, Wr2, ench2, hr, degf);
    edge_pass<<<EG, EB, 0, stream>>>(ei, ench2, s2);
    node2<<<NG, NB, 0, stream>>>(degf, s2, hr, b2, out);
}

// Round 4
// 307.969 us; speedup vs baseline: 2.2701x; 1.0102x over previous
//
#include <hip/hip_runtime.h>

#define N_NODES 100000
#define N_EDGES 2500000
#define NXCD 8

// pass-1 fixed point: fields [fy:28 | fx:28 | cnt:8], bias 16, scale 2^16
// per-edge biased value < (16+16)*2^16 = 2^21; deg <= 128 -> field sum < 2^28 (no carry)
#define B1 16.0f
#define S1 65536.0f
// pass-2 fixed point: fields [fy:32 | fx:32], bias 2048, scale 2^12
// per-edge biased value < (600+2048)*2^12 < 2^24; deg <= 128 -> sum < 2^31 (no carry)
#define B2 2048.0f
#define S2 4096.0f

typedef unsigned long long u64;
typedef unsigned int u32;

__device__ __forceinline__ u32 xcc_id() {
    u32 x;
    asm volatile("s_getreg_b32 %0, hwreg(HW_REG_XCC_ID)" : "=s"(x));
    return x & (NXCD - 1);
}

// ---------------------------------------------------------------------------
// Init: zero the 8-way replicated accumulator; encode x table
//   encx[i] = [ (y+B1)*S1 : 28 | (x+B1)*S1 : 28 | 1 : 8 ]
// ---------------------------------------------------------------------------
__global__ void init1(const float* __restrict__ x, u64* __restrict__ repl,
                      u64* __restrict__ encx) {
    int i = blockIdx.x * blockDim.x + threadIdx.x;
    if (i < NXCD * N_NODES) repl[i] = 0;
    if (i < N_NODES) {
        float2 v = reinterpret_cast<const float2*>(x)[i];
        u64 fx = (u64)(u32)((v.x + B1) * S1 + 0.5f);
        u64 fy = (u64)(u32)((v.y + B1) * S1 + 0.5f);
        encx[i] = (fy << 36) | (fx << 8) | 1ull;
    }
}

// ---------------------------------------------------------------------------
// Edge pass: repl[xcd][dst] += table[src]
// ONE u64 atomic per edge, WORKGROUP scope -> stays in the local XCD's TCC
// (no cross-XCD coherence traffic). Atomicity across the XCD is physical:
// all global atomics on an XCD execute at its shared TCC. Each XCD touches
// only its own replica slice, so no cross-XCD coherence is needed; the
// end-of-dispatch release makes dirty L2 lines visible to the next kernel.
// ---------------------------------------------------------------------------
__global__ void edge_pass(const int* __restrict__ ei, const u64* __restrict__ table,
                          u64* __restrict__ repl) {
    int e = blockIdx.x * blockDim.x + threadIdx.x;
    if (e >= N_EDGES) return;
    u32 slice = xcc_id() * N_NODES;
    int src = ei[e];
    int dst = ei[N_EDGES + e];
    u64 v = table[src];
    __hip_atomic_fetch_add(&repl[slice + dst], v, __ATOMIC_RELAXED,
                           __HIP_MEMORY_SCOPE_WORKGROUP);
}

// ---------------------------------------------------------------------------
// Node pass 1: sum 8 replicas, decode -> mean agg; hidden h in registers;
// emit encoded h2 table, hr = h@W_r2, degf; re-zero replicas for pass 2.
// ---------------------------------------------------------------------------
__global__ void node1(const float* __restrict__ x, u64* __restrict__ repl,
                      const float* __restrict__ Wl1, const float* __restrict__ Wr1,
                      const float* __restrict__ b1,
                      const float* __restrict__ Wl2, const float* __restrict__ Wr2,
                      u64* __restrict__ ench2, float2* __restrict__ hr,
                      float* __restrict__ degf) {
    __shared__ float sWl1[64], sWr1[64], sb1[32], sWl2[64], sWr2[64];
    int t = threadIdx.x;
    if (t < 64) {
        sWl1[t] = Wl1[t];
        sWr1[t] = Wr1[t];
        sWl2[t] = Wl2[t];
        sWr2[t] = Wr2[t];
    }
    if (t < 32) sb1[t] = b1[t];
    __syncthreads();

    int i = blockIdx.x * blockDim.x + t;
    if (i >= N_NODES) return;

    u64 v = 0;
#pragma unroll
    for (int k = 0; k < NXCD; ++k) {
        v += repl[k * N_NODES + i];
        repl[k * N_NODES + i] = 0;  // re-zero for pass 2
    }

    float cnt = (float)(u32)(v & 0xFFull);
    double fx = (double)(u32)((v >> 8) & 0xFFFFFFFull);
    double fy = (double)(v >> 36);
    float dinv = 1.0f / fmaxf(cnt, 1.0f);
    float ax = (float)(fx * (1.0 / 65536.0) - (double)cnt * 16.0) * dinv;
    float ay = (float)(fy * (1.0 / 65536.0) - (double)cnt * 16.0) * dinv;

    float2 xv = reinterpret_cast<const float2*>(x)[i];

    float h2a = 0.f, h2b = 0.f, hra = 0.f, hrb = 0.f;
#pragma unroll
    for (int f = 0; f < 32; ++f) {
        float h = ax * sWl1[f] + ay * sWl1[32 + f] + xv.x * sWr1[f] + xv.y * sWr1[32 + f] + sb1[f];
        h = fmaxf(h, 0.0f);
        h2a += h * sWl2[2 * f];
        h2b += h * sWl2[2 * f + 1];
        hra += h * sWr2[2 * f];
        hrb += h * sWr2[2 * f + 1];
    }
    u32 ex = (u32)((h2a + B2) * S2 + 0.5f);
    u32 ey = (u32)((h2b + B2) * S2 + 0.5f);
    ench2[i] = ((u64)ey << 32) | (u64)ex;
    hr[i] = make_float2(hra, hrb);
    degf[i] = cnt;
}

// ---------------------------------------------------------------------------
// Node pass 2: sum 8 replicas, decode, combine, log_softmax
// ---------------------------------------------------------------------------
__global__ void node2(const float* __restrict__ degf, const u64* __restrict__ repl,
                      const float2* __restrict__ hr, const float* __restrict__ b2,
                      float* __restrict__ out) {
    int i = blockIdx.x * blockDim.x + threadIdx.x;
    if (i >= N_NODES) return;

    u64 v = 0;
#pragma unroll
    for (int k = 0; k < NXCD; ++k) v += repl[k * N_NODES + i];

    float deg = degf[i];
    float dinv = 1.0f / fmaxf(deg, 1.0f);
    double fx = (double)(u32)(v & 0xFFFFFFFFull);
    double fy = (double)(v >> 32);
    float sx = (float)(fx * (1.0 / 4096.0) - (double)deg * 2048.0);
    float sy = (float)(fy * (1.0 / 4096.0) - (double)deg * 2048.0);
    float2 hv = hr[i];
    float o0 = sx * dinv + hv.x + b2[0];
    float o1 = sy * dinv + hv.y + b2[1];
    float m = fmaxf(o0, o1);
    float e0 = expf(o0 - m);
    float e1 = expf(o1 - m);
    float lse = logf(e0 + e1);
    reinterpret_cast<float2*>(out)[i] = make_float2(o0 - m - lse, o1 - m - lse);
}

extern "C" void kernel_launch(void* const* d_in, const int* in_sizes, int n_in,
                              void* d_out, int out_size, void* d_ws, size_t ws_size,
                              hipStream_t stream) {
    const float* x   = (const float*)d_in[0];
    const int*   ei  = (const int*)d_in[1];
    const float* Wl1 = (const float*)d_in[2];
    const float* Wr1 = (const float*)d_in[3];
    const float* b1  = (const float*)d_in[4];
    const float* Wl2 = (const float*)d_in[5];
    const float* Wr2 = (const float*)d_in[6];
    const float* b2  = (const float*)d_in[7];
    float* out = (float*)d_out;

    u64* w64 = (u64*)d_ws;
    u64* repl  = w64;                       // [8][N] replicated packed accumulators
    u64* encx  = w64 + NXCD * N_NODES;      // [N] encoded x table
    u64* ench2 = encx + N_NODES;            // [N] encoded h2 table
    float* fws  = (float*)(ench2 + N_NODES);
    float2* hr  = (float2*)fws;             // [N] float2
    float* degf = fws + 2 * N_NODES;        // [N]

    const int EB = 256;
    const int EG = (N_EDGES + EB - 1) / EB;
    const int NB = 256;
    const int NG = (N_NODES + NB - 1) / NB;
    const int IG = (NXCD * N_NODES + NB - 1) / NB;

    init1<<<IG, NB, 0, stream>>>(x, repl, encx);
    edge_pass<<<EG, EB, 0, stream>>>(ei, encx, repl);
    node1<<<NG, NB, 0, stream>>>(x, repl, Wl1, Wr1, b1, Wl2, Wr2, ench2, hr, degf);
    edge_pass<<<EG, EB, 0, stream>>>(ei, ench2, repl);
    node2<<<NG, NB, 0, stream>>>(degf, repl, hr, b2, out);
}

// Round 6
// 170.771 us; speedup vs baseline: 4.0939x; 1.8034x over previous
//
#include <hip/hip_runtime.h>

#define N_NODES 100000
#define N_EDGES 2500000
#define NPB 64                 // nodes per bucket
#define NBUC 1563              // ceil(N_NODES/NPB); bucket = dst>>6
#define SB 512                 // edge-chunk blocks for hist/scatter
#define EPB 4883               // ceil(N_EDGES/SB)
#define TOT (NBUC * SB)        // 800256 (k-major, b-minor count array)
#define P3B 782                // ceil(TOT/1024) scan blocks

// pass-1 fixed point: (x+16)*2^16; u32 sum ok (deg*20*2^16 < 2^32);
//   debiased signed sum |Σ x*2^16| < 2^31  -> decode via (int) cast
// pass-2 fixed point: (h2+2048)*2^12; u32 sum ok; |Σ h2*2^12| < 2^31 -> (int)

typedef unsigned int u32;

// ---------------------------------------------------------------------------
// S1: per-(bucket, block) histogram of dst buckets. LDS hist, no global atomics.
// ---------------------------------------------------------------------------
__global__ void hist_k(const int* __restrict__ ei, u32* __restrict__ histG) {
    __shared__ u32 hl[NBUC];
    int t = threadIdx.x, b = blockIdx.x;
    for (int k = t; k < NBUC; k += 256) hl[k] = 0;
    __syncthreads();
    int e0 = b * EPB, e1 = min(e0 + EPB, N_EDGES);
    for (int e = e0 + t; e < e1; e += 256) {
        int dst = ei[N_EDGES + e];
        atomicAdd(&hl[(u32)dst >> 6], 1u);
    }
    __syncthreads();
    for (int k = t; k < NBUC; k += 256) histG[k * SB + b] = hl[k];
}

// ---------------------------------------------------------------------------
// P1: per-1024-chunk sums of histG  -> blockSum[P3B]
// ---------------------------------------------------------------------------
__global__ void scan_p1(const u32* __restrict__ histG, u32* __restrict__ blockSum) {
    __shared__ u32 red[256];
    int t = threadIdx.x;
    int base = blockIdx.x * 1024;
    u32 s = 0;
#pragma unroll
    for (int j = 0; j < 4; ++j) {
        int idx = base + t * 4 + j;
        if (idx < TOT) s += histG[idx];
    }
    red[t] = s;
    __syncthreads();
    for (int off = 128; off > 0; off >>= 1) {
        if (t < off) red[t] += red[t + off];
        __syncthreads();
    }
    if (t == 0) blockSum[blockIdx.x] = red[0];
}

// ---------------------------------------------------------------------------
// P2: exclusive scan of blockSum[P3B] -> blockBase[P3B]  (one block)
// ---------------------------------------------------------------------------
__global__ void scan_p2(const u32* __restrict__ blockSum, u32* __restrict__ blockBase) {
    __shared__ u32 ts[256];
    int t = threadIdx.x;
    u32 v[4];
    u32 s = 0;
#pragma unroll
    for (int j = 0; j < 4; ++j) {
        int idx = t * 4 + j;
        v[j] = (idx < P3B) ? blockSum[idx] : 0u;
        s += v[j];
    }
    ts[t] = s;
    __syncthreads();
    for (int off = 1; off < 256; off <<= 1) {
        u32 add = (t >= off) ? ts[t - off] : 0u;
        __syncthreads();
        ts[t] += add;
        __syncthreads();
    }
    u32 run = (t > 0) ? ts[t - 1] : 0u;
#pragma unroll
    for (int j = 0; j < 4; ++j) {
        int idx = t * 4 + j;
        if (idx < P3B) blockBase[idx] = run;
        run += v[j];
    }
}

// ---------------------------------------------------------------------------
// P3: in-place exclusive scan of histG chunks, offset by blockBase
// ---------------------------------------------------------------------------
__global__ void scan_p3(u32* histG, const u32* __restrict__ blockBase) {
    __shared__ u32 ts[256];
    int t = threadIdx.x;
    int base = blockIdx.x * 1024;
    u32 v[4];
    u32 s = 0;
#pragma unroll
    for (int j = 0; j < 4; ++j) {
        int idx = base + t * 4 + j;
        v[j] = (idx < TOT) ? histG[idx] : 0u;
        s += v[j];
    }
    ts[t] = s;
    __syncthreads();
    for (int off = 1; off < 256; off <<= 1) {
        u32 add = (t >= off) ? ts[t - off] : 0u;
        __syncthreads();
        ts[t] += add;
        __syncthreads();
    }
    u32 run = ((t > 0) ? ts[t - 1] : 0u) + blockBase[blockIdx.x];
#pragma unroll
    for (int j = 0; j < 4; ++j) {
        int idx = base + t * 4 + j;
        if (idx < TOT) histG[idx] = run;
        run += v[j];
    }
}

// ---------------------------------------------------------------------------
// S3: scatter edges into bucket-sorted order. Positions claimed via LDS atomics
// from the scanned (bucket,block) bases -> slot ranges are block-exclusive.
// Packed edge: (dst&63)<<17 | src   (src < 2^17)
// ---------------------------------------------------------------------------
__global__ void scatter_k(const int* __restrict__ ei, const u32* __restrict__ histG,
                          u32* __restrict__ sortedE) {
    __shared__ u32 pos[NBUC];
    int t = threadIdx.x, b = blockIdx.x;
    for (int k = t; k < NBUC; k += 256) pos[k] = histG[k * SB + b];
    __syncthreads();
    int e0 = b * EPB, e1 = min(e0 + EPB, N_EDGES);
    for (int e = e0 + t; e < e1; e += 256) {
        int src = ei[e];
        int dst = ei[N_EDGES + e];
        u32 k = (u32)dst >> 6;
        u32 slot = atomicAdd(&pos[k], 1u);
        sortedE[slot] = (((u32)dst & 63u) << 17) | (u32)src;
    }
}

// ---------------------------------------------------------------------------
// A1: bucket-local aggregation of x (LDS u32 fixed-point) + fused node layer 1.
// Emits h2 = relu(h)@W_l2, hr = relu(h)@W_r2, deg.
// ---------------------------------------------------------------------------
__global__ void agg1_node1(const u32* __restrict__ sortedE, const u32* __restrict__ histG,
                           const float* __restrict__ x,
                           const float* __restrict__ Wl1, const float* __restrict__ Wr1,
                           const float* __restrict__ b1,
                           const float* __restrict__ Wl2, const float* __restrict__ Wr2,
                           float2* __restrict__ h2G, float2* __restrict__ hrG,
                           float* __restrict__ degG) {
    __shared__ u32 cntL[NPB], fxL[NPB], fyL[NPB];
    __shared__ float sWl1[64], sWr1[64], sb1[32], sWl2[64], sWr2[64];
    int t = threadIdx.x, k = blockIdx.x;
    if (t < 64) { sWl1[t] = Wl1[t]; sWr1[t] = Wr1[t]; sWl2[t] = Wl2[t]; sWr2[t] = Wr2[t]; }
    if (t >= 64 && t < 96) sb1[t - 64] = b1[t - 64];
    if (t >= 96 && t < 96 + NPB) { cntL[t - 96] = 0; fxL[t - 96] = 0; fyL[t - 96] = 0; }
    __syncthreads();

    u32 start = histG[k * SB];
    u32 end = (k + 1 < NBUC) ? histG[(k + 1) * SB] : N_EDGES;
    const float2* x2 = (const float2*)x;
    for (u32 idx = start + t; idx < end; idx += 256) {
        u32 p = sortedE[idx];
        u32 src = p & 0x1FFFFu;
        u32 loc = p >> 17;
        float2 v = x2[src];
        atomicAdd(&fxL[loc], (u32)((v.x + 16.0f) * 65536.0f + 0.5f));
        atomicAdd(&fyL[loc], (u32)((v.y + 16.0f) * 65536.0f + 0.5f));
        atomicAdd(&cntL[loc], 1u);
    }
    __syncthreads();

    if (t < NPB) {
        int i = k * NPB + t;
        if (i < N_NODES) {
            u32 cnt = cntL[t];
            float fc = (float)cnt;
            float dinv = 1.0f / fmaxf(fc, 1.0f);
            // debias: (fxL - cnt*16*2^16) is SIGNED mod 2^32 -> recover via int cast
            float ax = (float)(int)(fxL[t] - cnt * 1048576u) * (1.0f / 65536.0f) * dinv;
            float ay = (float)(int)(fyL[t] - cnt * 1048576u) * (1.0f / 65536.0f) * dinv;
            float2 xv = x2[i];
            float h2a = 0.f, h2b = 0.f, hra = 0.f, hrb = 0.f;
#pragma unroll
            for (int f = 0; f < 32; ++f) {
                float h = ax * sWl1[f] + ay * sWl1[32 + f] + xv.x * sWr1[f] + xv.y * sWr1[32 + f] + sb1[f];
                h = fmaxf(h, 0.0f);
                h2a += h * sWl2[2 * f];
                h2b += h * sWl2[2 * f + 1];
                hra += h * sWr2[2 * f];
                hrb += h * sWr2[2 * f + 1];
            }
            h2G[i] = make_float2(h2a, h2b);
            hrG[i] = make_float2(hra, hrb);
            degG[i] = fc;
        }
    }
}

// ---------------------------------------------------------------------------
// A2: bucket-local aggregation of h2 + fused node layer 2 + log_softmax.
// ---------------------------------------------------------------------------
__global__ void agg2_node2(const u32* __restrict__ sortedE, const u32* __restrict__ histG,
                           const float2* __restrict__ h2G, const float2* __restrict__ hrG,
                           const float* __restrict__ degG, const float* __restrict__ b2,
                           float* __restrict__ out) {
    __shared__ u32 gxL[NPB], gyL[NPB];
    int t = threadIdx.x, k = blockIdx.x;
    if (t < NPB) { gxL[t] = 0; gyL[t] = 0; }
    __syncthreads();

    u32 start = histG[k * SB];
    u32 end = (k + 1 < NBUC) ? histG[(k + 1) * SB] : N_EDGES;
    for (u32 idx = start + t; idx < end; idx += 256) {
        u32 p = sortedE[idx];
        u32 src = p & 0x1FFFFu;
        u32 loc = p >> 17;
        float2 v = h2G[src];
        atomicAdd(&gxL[loc], (u32)((v.x + 2048.0f) * 4096.0f + 0.5f));
        atomicAdd(&gyL[loc], (u32)((v.y + 2048.0f) * 4096.0f + 0.5f));
    }
    __syncthreads();

    if (t < NPB) {
        int i = k * NPB + t;
        if (i < N_NODES) {
            float cnt = degG[i];
            u32 c = (u32)cnt;
            float dinv = 1.0f / fmaxf(cnt, 1.0f);
            // debias: (gxL - cnt*2048*2^12) is SIGNED mod 2^32 -> int cast
            float sx = (float)(int)(gxL[t] - c * 8388608u) * (1.0f / 4096.0f) * dinv;
            float sy = (float)(int)(gyL[t] - c * 8388608u) * (1.0f / 4096.0f) * dinv;
            float2 hv = hrG[i];
            float o0 = sx + hv.x + b2[0];
            float o1 = sy + hv.y + b2[1];
            float m = fmaxf(o0, o1);
            float e0 = expf(o0 - m);
            float e1 = expf(o1 - m);
            float lse = logf(e0 + e1);
            ((float2*)out)[i] = make_float2(o0 - m - lse, o1 - m - lse);
        }
    }
}

extern "C" void kernel_launch(void* const* d_in, const int* in_sizes, int n_in,
                              void* d_out, int out_size, void* d_ws, size_t ws_size,
                              hipStream_t stream) {
    const float* x   = (const float*)d_in[0];
    const int*   ei  = (const int*)d_in[1];
    const float* Wl1 = (const float*)d_in[2];
    const float* Wr1 = (const float*)d_in[3];
    const float* b1  = (const float*)d_in[4];
    const float* Wl2 = (const float*)d_in[5];
    const float* Wr2 = (const float*)d_in[6];
    const float* b2  = (const float*)d_in[7];
    float* out = (float*)d_out;

    u32* histG      = (u32*)d_ws;            // [NBUC*SB], scanned in place
    u32* blockSum   = histG + TOT;           // [P3B]
    u32* blockBase  = blockSum + P3B;        // [P3B]
    u32* sortedE    = blockBase + P3B;       // [N_EDGES]
    float2* h2G     = (float2*)(sortedE + N_EDGES);  // [N] (offset is 8B-aligned)
    float2* hrG     = h2G + N_NODES;         // [N]
    float* degG     = (float*)(hrG + N_NODES);  // [N]
    // total ws use ~15.2 MB

    hist_k    <<<SB,   256, 0, stream>>>(ei, histG);
    scan_p1   <<<P3B,  256, 0, stream>>>(histG, blockSum);
    scan_p2   <<<1,    256, 0, stream>>>(blockSum, blockBase);
    scan_p3   <<<P3B,  256, 0, stream>>>(histG, blockBase);
    scatter_k <<<SB,   256, 0, stream>>>(ei, histG, sortedE);
    agg1_node1<<<NBUC, 256, 0, stream>>>(sortedE, histG, x, Wl1, Wr1, b1, Wl2, Wr2,
                                         h2G, hrG, degG);
    agg2_node2<<<NBUC, 256, 0, stream>>>(sortedE, histG, h2G, hrG, degG, b2, out);
}

// Round 7
// 148.283 us; speedup vs baseline: 4.7148x; 1.1517x over previous
//
#include <hip/hip_runtime.h>

#define N_NODES 100000
#define N_EDGES 2500000
#define SBBITS 11
#define SBSZ 2048              // nodes per superbucket
#define NSB 49                 // ceil(N_NODES/2048)
#define SB 512                 // edge-chunk blocks for hist/scatter
#define EPB 4883               // ceil(N_EDGES/SB)
#define TOT (NSB * SB)         // 25088 (sb-major, block-minor)
#define P1B 25                 // ceil(TOT/1024)
#define M 16                   // agg blocks per superbucket
#define AGG_GRID (NSB * M)     // 784

// pass-1 fixed point: (x+16)*2^16; u32 sum ok (deg*32*2^16 < 2^32);
//   debiased signed sum |Σ x*2^16| < 2^31 -> decode via (int) cast  [R6-validated]
// pass-2 fixed point: (h2+2048)*2^12; |Σ h2*2^12| < 2^31 -> (int)   [R6-validated]

typedef unsigned int u32;
typedef unsigned long long u64;

// ---------------------------------------------------------------------------
// S1: per-(superbucket, block) histogram. 8-way replicated LDS counters.
// ---------------------------------------------------------------------------
__global__ void hist_k(const int* __restrict__ ei, u32* __restrict__ histG) {
    __shared__ u32 hl[NSB * 8];
    int t = threadIdx.x, b = blockIdx.x;
    for (int k = t; k < NSB * 8; k += 256) hl[k] = 0;
    __syncthreads();
    int e0 = b * EPB, e1 = min(e0 + EPB, N_EDGES);
    int r = t & 7;
    for (int e = e0 + t; e < e1; e += 256) {
        u32 dst = (u32)ei[N_EDGES + e];
        atomicAdd(&hl[(dst >> SBBITS) * 8 + r], 1u);
    }
    __syncthreads();
    for (int k = t; k < NSB; k += 256) {
        u32 s = 0;
#pragma unroll
        for (int j = 0; j < 8; ++j) s += hl[k * 8 + j];
        histG[k * SB + b] = s;
    }
}

// ---------------------------------------------------------------------------
// P1: per-1024-chunk sums of histG -> blockSum[P1B]
// ---------------------------------------------------------------------------
__global__ void scan_p1(const u32* __restrict__ histG, u32* __restrict__ blockSum) {
    __shared__ u32 red[256];
    int t = threadIdx.x;
    int base = blockIdx.x * 1024;
    u32 s = 0;
#pragma unroll
    for (int j = 0; j < 4; ++j) {
        int idx = base + t * 4 + j;
        if (idx < TOT) s += histG[idx];
    }
    red[t] = s;
    __syncthreads();
    for (int off = 128; off > 0; off >>= 1) {
        if (t < off) red[t] += red[t + off];
        __syncthreads();
    }
    if (t == 0) blockSum[blockIdx.x] = red[0];
}

// ---------------------------------------------------------------------------
// P2: exclusive scan of blockSum[P1B] (one block)
// ---------------------------------------------------------------------------
__global__ void scan_p2(const u32* __restrict__ blockSum, u32* __restrict__ blockBase) {
    __shared__ u32 ts[256];
    int t = threadIdx.x;
    u32 v[4];
    u32 s = 0;
#pragma unroll
    for (int j = 0; j < 4; ++j) {
        int idx = t * 4 + j;
        v[j] = (idx < P1B) ? blockSum[idx] : 0u;
        s += v[j];
    }
    ts[t] = s;
    __syncthreads();
    for (int off = 1; off < 256; off <<= 1) {
        u32 add = (t >= off) ? ts[t - off] : 0u;
        __syncthreads();
        ts[t] += add;
        __syncthreads();
    }
    u32 run = (t > 0) ? ts[t - 1] : 0u;
#pragma unroll
    for (int j = 0; j < 4; ++j) {
        int idx = t * 4 + j;
        if (idx < P1B) blockBase[idx] = run;
        run += v[j];
    }
}

// ---------------------------------------------------------------------------
// P3: in-place exclusive scan of histG chunks, offset by blockBase
// ---------------------------------------------------------------------------
__global__ void scan_p3(u32* histG, const u32* __restrict__ blockBase) {
    __shared__ u32 ts[256];
    int t = threadIdx.x;
    int base = blockIdx.x * 1024;
    u32 v[4];
    u32 s = 0;
#pragma unroll
    for (int j = 0; j < 4; ++j) {
        int idx = base + t * 4 + j;
        v[j] = (idx < TOT) ? histG[idx] : 0u;
        s += v[j];
    }
    ts[t] = s;
    __syncthreads();
    for (int off = 1; off < 256; off <<= 1) {
        u32 add = (t >= off) ? ts[t - off] : 0u;
        __syncthreads();
        ts[t] += add;
        __syncthreads();
    }
    u32 run = ((t > 0) ? ts[t - 1] : 0u) + blockBase[blockIdx.x];
#pragma unroll
    for (int j = 0; j < 4; ++j) {
        int idx = base + t * 4 + j;
        if (idx < TOT) histG[idx] = run;
        run += v[j];
    }
}

// ---------------------------------------------------------------------------
// S3: scatter edges into superbucket order. Runs per (sb,block) ~100 edges
// = 400 B -> full-line writes, per-XCD write set ~1.3 MB < 4 MB L2.
// Packed edge: (dst&2047)<<17 | src   (11+17 = 28 bits)
// ---------------------------------------------------------------------------
__global__ void scatter_k(const int* __restrict__ ei, const u32* __restrict__ histG,
                          u32* __restrict__ sortedE) {
    __shared__ u32 pos[NSB];
    int t = threadIdx.x, b = blockIdx.x;
    if (t < NSB) pos[t] = histG[t * SB + b];
    __syncthreads();
    int e0 = b * EPB, e1 = min(e0 + EPB, N_EDGES);
    for (int e = e0 + t; e < e1; e += 256) {
        u32 src = (u32)ei[e];
        u32 dst = (u32)ei[N_EDGES + e];
        u32 sb = dst >> SBBITS;
        u32 slot = atomicAdd(&pos[sb], 1u);
        sortedE[slot] = ((dst & (SBSZ - 1u)) << 17) | src;
    }
}

// ---------------------------------------------------------------------------
// A1: partial aggregation of x over one superbucket slice. LDS fixed-point.
// Writes coalesced partials PART[blk][3][2048].
// ---------------------------------------------------------------------------
__global__ void agg1_k(const u32* __restrict__ sortedE, const u32* __restrict__ histG,
                       const float* __restrict__ x, u32* __restrict__ PART) {
    __shared__ u32 cntL[SBSZ], fxL[SBSZ], fyL[SBSZ];
    int t = threadIdx.x;
    u32 sb = blockIdx.x / M, m = blockIdx.x % M;
    for (int j = t; j < SBSZ; j += 256) { cntL[j] = 0; fxL[j] = 0; fyL[j] = 0; }
    __syncthreads();

    u32 s0 = histG[sb * SB];
    u32 s1 = (sb + 1 < NSB) ? histG[(sb + 1) * SB] : N_EDGES;
    u32 len = s1 - s0;
    u32 a = s0 + len * m / M;
    u32 bEnd = s0 + len * (m + 1) / M;
    const float2* x2 = (const float2*)x;

    u32 idx = a + t;
    while (idx + 256 < bEnd) {           // 2-way unrolled for gather ILP
        u32 p0 = sortedE[idx], p1 = sortedE[idx + 256];
        float2 v0 = x2[p0 & 0x1FFFFu];
        float2 v1 = x2[p1 & 0x1FFFFu];
        u32 l0 = p0 >> 17, l1 = p1 >> 17;
        atomicAdd(&cntL[l0], 1u);
        atomicAdd(&fxL[l0], (u32)((v0.x + 16.0f) * 65536.0f + 0.5f));
        atomicAdd(&fyL[l0], (u32)((v0.y + 16.0f) * 65536.0f + 0.5f));
        atomicAdd(&cntL[l1], 1u);
        atomicAdd(&fxL[l1], (u32)((v1.x + 16.0f) * 65536.0f + 0.5f));
        atomicAdd(&fyL[l1], (u32)((v1.y + 16.0f) * 65536.0f + 0.5f));
        idx += 512;
    }
    if (idx < bEnd) {
        u32 p = sortedE[idx];
        float2 v = x2[p & 0x1FFFFu];
        u32 l = p >> 17;
        atomicAdd(&cntL[l], 1u);
        atomicAdd(&fxL[l], (u32)((v.x + 16.0f) * 65536.0f + 0.5f));
        atomicAdd(&fyL[l], (u32)((v.y + 16.0f) * 65536.0f + 0.5f));
    }
    __syncthreads();

    u32 base = blockIdx.x * (3 * SBSZ);
    for (int j = t; j < SBSZ; j += 256) {
        PART[base + j] = cntL[j];
        PART[base + SBSZ + j] = fxL[j];
        PART[base + 2 * SBSZ + j] = fyL[j];
    }
}

// ---------------------------------------------------------------------------
// R1: sum M partials per node, decode, fused node layer 1.
// Emits ench2 (u64 packed encoded h2), hr, deg.
// ---------------------------------------------------------------------------
__global__ void reduce1_node1(const u32* __restrict__ PART, const float* __restrict__ x,
                              const float* __restrict__ Wl1, const float* __restrict__ Wr1,
                              const float* __restrict__ b1,
                              const float* __restrict__ Wl2, const float* __restrict__ Wr2,
                              u64* __restrict__ ench2, float2* __restrict__ hrG,
                              float* __restrict__ degG) {
    __shared__ float sWl1[64], sWr1[64], sb1[32], sWl2[64], sWr2[64];
    int t = threadIdx.x;
    if (t < 64) { sWl1[t] = Wl1[t]; sWr1[t] = Wr1[t]; sWl2[t] = Wl2[t]; sWr2[t] = Wr2[t]; }
    if (t >= 64 && t < 96) sb1[t - 64] = b1[t - 64];
    __syncthreads();

    int i = blockIdx.x * 256 + t;
    if (i >= N_NODES) return;
    u32 sb = (u32)i >> SBBITS, j = (u32)i & (SBSZ - 1u);

    u32 cnt = 0, fx = 0, fy = 0;
#pragma unroll
    for (int m = 0; m < M; ++m) {
        u32 base = (sb * M + m) * (3 * SBSZ);
        cnt += PART[base + j];
        fx += PART[base + SBSZ + j];
        fy += PART[base + 2 * SBSZ + j];
    }

    float fc = (float)cnt;
    float dinv = 1.0f / fmaxf(fc, 1.0f);
    float ax = (float)(int)(fx - cnt * 1048576u) * (1.0f / 65536.0f) * dinv;
    float ay = (float)(int)(fy - cnt * 1048576u) * (1.0f / 65536.0f) * dinv;
    float2 xv = ((const float2*)x)[i];

    float h2a = 0.f, h2b = 0.f, hra = 0.f, hrb = 0.f;
#pragma unroll
    for (int f = 0; f < 32; ++f) {
        float h = ax * sWl1[f] + ay * sWl1[32 + f] + xv.x * sWr1[f] + xv.y * sWr1[32 + f] + sb1[f];
        h = fmaxf(h, 0.0f);
        h2a += h * sWl2[2 * f];
        h2b += h * sWl2[2 * f + 1];
        hra += h * sWr2[2 * f];
        hrb += h * sWr2[2 * f + 1];
    }
    u32 ex = (u32)((h2a + 2048.0f) * 4096.0f + 0.5f);
    u32 ey = (u32)((h2b + 2048.0f) * 4096.0f + 0.5f);
    ench2[i] = ((u64)ey << 32) | (u64)ex;
    hrG[i] = make_float2(hra, hrb);
    degG[i] = fc;
}

// ---------------------------------------------------------------------------
// A2: partial aggregation of encoded h2 (one u64 gather/edge).
// Writes PART2[blk][2][2048] (aliased onto PART1 memory).
// ---------------------------------------------------------------------------
__global__ void agg2_k(const u32* __restrict__ sortedE, const u32* __restrict__ histG,
                       const u64* __restrict__ ench2, u32* __restrict__ PART2) {
    __shared__ u32 gxL[SBSZ], gyL[SBSZ];
    int t = threadIdx.x;
    u32 sb = blockIdx.x / M, m = blockIdx.x % M;
    for (int j = t; j < SBSZ; j += 256) { gxL[j] = 0; gyL[j] = 0; }
    __syncthreads();

    u32 s0 = histG[sb * SB];
    u32 s1 = (sb + 1 < NSB) ? histG[(sb + 1) * SB] : N_EDGES;
    u32 len = s1 - s0;
    u32 a = s0 + len * m / M;
    u32 bEnd = s0 + len * (m + 1) / M;

    u32 idx = a + t;
    while (idx + 256 < bEnd) {
        u32 p0 = sortedE[idx], p1 = sortedE[idx + 256];
        u64 e0 = ench2[p0 & 0x1FFFFu];
        u64 e1 = ench2[p1 & 0x1FFFFu];
        u32 l0 = p0 >> 17, l1 = p1 >> 17;
        atomicAdd(&gxL[l0], (u32)e0);
        atomicAdd(&gyL[l0], (u32)(e0 >> 32));
        atomicAdd(&gxL[l1], (u32)e1);
        atomicAdd(&gyL[l1], (u32)(e1 >> 32));
        idx += 512;
    }
    if (idx < bEnd) {
        u32 p = sortedE[idx];
        u64 e = ench2[p & 0x1FFFFu];
        u32 l = p >> 17;
        atomicAdd(&gxL[l], (u32)e);
        atomicAdd(&gyL[l], (u32)(e >> 32));
    }
    __syncthreads();

    u32 base = blockIdx.x * (2 * SBSZ);
    for (int j = t; j < SBSZ; j += 256) {
        PART2[base + j] = gxL[j];
        PART2[base + SBSZ + j] = gyL[j];
    }
}

// ---------------------------------------------------------------------------
// R2: sum M partials, decode, combine with hr + b2, log_softmax.
// ---------------------------------------------------------------------------
__global__ void reduce2_node2(const u32* __restrict__ PART2, const float2* __restrict__ hrG,
                              const float* __restrict__ degG, const float* __restrict__ b2,
                              float* __restrict__ out) {
    int i = blockIdx.x * 256 + threadIdx.x;
    if (i >= N_NODES) return;
    u32 sb = (u32)i >> SBBITS, j = (u32)i & (SBSZ - 1u);

    u32 gx = 0, gy = 0;
#pragma unroll
    for (int m = 0; m < M; ++m) {
        u32 base = (sb * M + m) * (2 * SBSZ);
        gx += PART2[base + j];
        gy += PART2[base + SBSZ + j];
    }

    float fc = degG[i];
    u32 c = (u32)fc;
    float dinv = 1.0f / fmaxf(fc, 1.0f);
    float sx = (float)(int)(gx - c * 8388608u) * (1.0f / 4096.0f) * dinv;
    float sy = (float)(int)(gy - c * 8388608u) * (1.0f / 4096.0f) * dinv;
    float2 hv = hrG[i];
    float o0 = sx + hv.x + b2[0];
    float o1 = sy + hv.y + b2[1];
    float mx = fmaxf(o0, o1);
    float e0 = expf(o0 - mx);
    float e1 = expf(o1 - mx);
    float lse = logf(e0 + e1);
    ((float2*)out)[i] = make_float2(o0 - mx - lse, o1 - mx - lse);
}

extern "C" void kernel_launch(void* const* d_in, const int* in_sizes, int n_in,
                              void* d_out, int out_size, void* d_ws, size_t ws_size,
                              hipStream_t stream) {
    const float* x   = (const float*)d_in[0];
    const int*   ei  = (const int*)d_in[1];
    const float* Wl1 = (const float*)d_in[2];
    const float* Wr1 = (const float*)d_in[3];
    const float* b1  = (const float*)d_in[4];
    const float* Wl2 = (const float*)d_in[5];
    const float* Wr2 = (const float*)d_in[6];
    const float* b2  = (const float*)d_in[7];
    float* out = (float*)d_out;

    u32* histG     = (u32*)d_ws;               // [25088]
    u32* blockSum  = histG + TOT;              // [32]
    u32* blockBase = blockSum + 32;            // [32]
    u32* sortedE   = blockBase + 32;           // [2.5M]   off 25152
    u32* PART      = sortedE + N_EDGES;        // [784*6144] = 19.3 MB (PART2 aliased)
    u64* ench2     = (u64*)(PART + AGG_GRID * 3 * SBSZ);  // [N] u64 (offset even -> 8B ok)
    float2* hrG    = (float2*)(ench2 + N_NODES);          // [N]
    float* degG    = (float*)(hrG + N_NODES);             // [N]
    // total ws use ~31.4 MB

    hist_k  <<<SB,  256, 0, stream>>>(ei, histG);
    scan_p1 <<<P1B, 256, 0, stream>>>(histG, blockSum);
    scan_p2 <<<1,   256, 0, stream>>>(blockSum, blockBase);
    scan_p3 <<<P1B, 256, 0, stream>>>(histG, blockBase);
    scatter_k<<<SB, 256, 0, stream>>>(ei, histG, sortedE);
    agg1_k  <<<AGG_GRID, 256, 0, stream>>>(sortedE, histG, x, PART);
    reduce1_node1<<<(N_NODES + 255) / 256, 256, 0, stream>>>(PART, x, Wl1, Wr1, b1,
                                                             Wl2, Wr2, ench2, hrG, degG);
    agg2_k  <<<AGG_GRID, 256, 0, stream>>>(sortedE, histG, ench2, PART);
    reduce2_node2<<<(N_NODES + 255) / 256, 256, 0, stream>>>(PART, hrG, degG, b2, out);
}